// Round 14
// baseline (186.513 us; speedup 1.0000x reference)
//
#include <hip/hip_runtime.h>

// RIIDModelLSTM: 2-layer LSTM (H=6), T=512, B=8192, fused FC(6->32->1) head.
//
// v14 = v13 (179.4us) + ONE-STEP LAYER DECOUPLING (software pipeline).
// Ledger: 841 cyc/step = 661 busy (census floor) + 180 serial-chain residue.
// The residue persists because cell0(t) -> cell1(t) run as ONE serial chain
// per step. But loop0 (h0,c0) and loop1 (h1,c1) are separate recursions;
// cell1 may lag one step. v14 body:
//   A: cell1(t-1)  -- inputs h1p=h1(t-2), h0p=h0(t-1), ready at body start
//   B: cell0(t)    -- from exps hoisted at step t-1; gathers new h0p
//   C: gates0(t+1) -- bias + x(t+1) + wh0*h0(t); close; hoist 4 exps
//   D: FC(t-1)     -- on h1p gathered by A
// A->D and B->C are independent chains that fill each other's latency
// windows. Same ops, same per-value order, one step later => bit-identical.
// Prologue: cell0(0) only. Main loop t=1..508 (127 x 4-unroll). Peeled
// t=509..511, epilogue cell1(511)+FC(511).
// Mapping unchanged: 8-lane coset/seq, zero-DS, DPP-only, pk-asm,
// 1024 waves = 1 wave/SIMD.

typedef float v2f __attribute__((ext_vector_type(2)));

static constexpr float L2E  = 1.44269504088896340736f;
static constexpr float TL2E = 2.0f * L2E;

#define DPP_QP(a,b,c,d) ((a)|((b)<<2)|((c)<<4)|((d)<<6))
#define DPP_X1  DPP_QP(1,0,3,2)   // quad_perm xor-1
#define DPP_X2  DPP_QP(2,3,0,1)   // quad_perm xor-2
#define DPP_B0  DPP_QP(0,0,0,0)   // quad bcast lane0
#define DPP_B1  DPP_QP(1,1,1,1)
#define DPP_B2  DPP_QP(2,2,2,2)
#define DPP_B3  DPP_QP(3,3,3,3)
#define DPP_X8  0x128             // row_ror:8 = lane xor 8 inside 16-row

template<int CTRL>
__device__ __forceinline__ float dppf(float v) {
    return __int_as_float(__builtin_amdgcn_update_dpp(
        0, __float_as_int(v), CTRL, 0xF, 0xF, true));
}

#define PIN(v) asm volatile("" : "+v"(v))

#define PKFMA_LO(d,a,b) asm("v_pk_fma_f32 %0, %1, %2, %0 op_sel:[0,0,0] op_sel_hi:[1,0,1]" : "+v"(d) : "v"(a), "v"(b))
#define PKFMA_HI(d,a,b) asm("v_pk_fma_f32 %0, %1, %2, %0 op_sel:[0,1,0] op_sel_hi:[1,1,1]" : "+v"(d) : "v"(a), "v"(b))
#define PKADD(d,a,b)    asm("v_pk_add_f32 %0, %1, %2" : "=v"(d) : "v"(a), "v"(b))

// 12 pk_fma: dst/dst2 += W[0..5] * S[0..2] (lo/hi split), S = v2f[3]
#define ACC12(DST_, DST2_, W_, S_)                              \
    PKFMA_LO(DST_, W_[0], S_[0]); PKFMA_HI(DST2_, W_[1], S_[0]); \
    PKFMA_LO(DST_, W_[2], S_[1]); PKFMA_HI(DST2_, W_[3], S_[1]); \
    PKFMA_LO(DST_, W_[4], S_[2]); PKFMA_HI(DST2_, W_[5], S_[2])

// sigmoid from e = exp2(-L2E*x):  1/(1+e)
__device__ __forceinline__ float sig_from_e(float e) {
    return __builtin_amdgcn_rcpf(1.0f + e);
}
// tanh from e = exp2(2*L2E*x):  1 - 2/(1+e)
__device__ __forceinline__ float tanh_from_e(float e) {
    return fmaf(-2.0f, __builtin_amdgcn_rcpf(1.0f + e), 1.0f);
}
// tanh with +2*L2E pre-folded (for tanh(c))
__device__ __forceinline__ float tanh_pre(float a) {
    return fmaf(-2.0f, __builtin_amdgcn_rcpf(1.0f + __builtin_amdgcn_exp2f(a)), 1.0f);
}

extern "C" __global__ void __launch_bounds__(64)
__attribute__((amdgpu_waves_per_eu(1, 1)))
lstm_dpp8v14(const float* __restrict__ x,
             const float* __restrict__ wih0, const float* __restrict__ whh0,
             const float* __restrict__ bih0, const float* __restrict__ bhh0,
             const float* __restrict__ wih1, const float* __restrict__ whh1,
             const float* __restrict__ bih1, const float* __restrict__ bhh1,
             const float* __restrict__ fc1w, const float* __restrict__ fc1b,
             const float* __restrict__ fc2w, const float* __restrict__ fc2b,
             float* __restrict__ out, int nbatch)
{
    const int L   = threadIdx.x;                 // 0..63
    const int l   = L & 15;
    const int row = L >> 4;                      // 0..3
    const int cst = (l >> 2) & 1;                // coset within row
    const int p   = (l & 3) | ((l >> 3) << 2);   // position in coset, 0..7
    const bool lowq = ((L >> 3) & 1) == 0;       // lane in units-0..3 quad

    int seq = blockIdx.x * 8 + row * 2 + cst;
    const bool live = (seq < nbatch);
    if (!live) seq = nbatch - 1;

    const float km = (p < 6) ? 1.0f : 0.0f;      // pad lanes 6,7
    const int   k  = (p < 6) ? p : 0;
    const int ir = k, fr = 6 + k, gr = 12 + k, orr = 18 + k;  // i,f,g,o rows

    // ---- weights. A=[i,f] (sigmoid,-L2E | sigmoid,-L2E),
    //               B=[g,o] (tanh,+2L2E | sigmoid,-L2E). Unit-ordered slots.
    v2f wiA0[6], wiB0[6];
    v2f whA0[6], whB0[6], wiA1[6], wiB1[6], whA1[6], whB1[6], f1wA[6], f1wB[6];
#pragma unroll
    for (int j = 0; j < 6; ++j) {
        wiA0[j] = (v2f){ wih0[ir*6+j]*(-L2E)*km,  wih0[fr*6+j]*(-L2E)*km };
        wiB0[j] = (v2f){ wih0[gr*6+j]*( TL2E)*km, wih0[orr*6+j]*(-L2E)*km };
        whA0[j] = (v2f){ whh0[ir*6+j]*(-L2E)*km,  whh0[fr*6+j]*(-L2E)*km };
        whB0[j] = (v2f){ whh0[gr*6+j]*( TL2E)*km, whh0[orr*6+j]*(-L2E)*km };
        wiA1[j] = (v2f){ wih1[ir*6+j]*(-L2E)*km,  wih1[fr*6+j]*(-L2E)*km };
        wiB1[j] = (v2f){ wih1[gr*6+j]*( TL2E)*km, wih1[orr*6+j]*(-L2E)*km };
        whA1[j] = (v2f){ whh1[ir*6+j]*(-L2E)*km,  whh1[fr*6+j]*(-L2E)*km };
        whB1[j] = (v2f){ whh1[gr*6+j]*( TL2E)*km, whh1[orr*6+j]*(-L2E)*km };
        f1wA[j] = (v2f){ fc1w[(4*p+0)*6+j], fc1w[(4*p+1)*6+j] };
        f1wB[j] = (v2f){ fc1w[(4*p+2)*6+j], fc1w[(4*p+3)*6+j] };
    }
    v2f bbA0 = (v2f){ (bih0[ir]+bhh0[ir])*(-L2E)*km,  (bih0[fr]+bhh0[fr])*(-L2E)*km };
    v2f bbB0 = (v2f){ (bih0[gr]+bhh0[gr])*( TL2E)*km, (bih0[orr]+bhh0[orr])*(-L2E)*km };
    v2f bbA1 = (v2f){ (bih1[ir]+bhh1[ir])*(-L2E)*km,  (bih1[fr]+bhh1[fr])*(-L2E)*km };
    v2f bbB1 = (v2f){ (bih1[gr]+bhh1[gr])*( TL2E)*km, (bih1[orr]+bhh1[orr])*(-L2E)*km };
    v2f f1bA = (v2f){ fc1b[4*p+0], fc1b[4*p+1] };
    v2f f1bB = (v2f){ fc1b[4*p+2], fc1b[4*p+3] };
    v2f f2wA = (v2f){ fc2w[4*p+0], fc2w[4*p+1] };
    v2f f2wB = (v2f){ fc2w[4*p+2], fc2w[4*p+3] };
    float f2b = fc2b[0];

#pragma unroll
    for (int j = 0; j < 6; ++j) {
        PIN(wiA0[j]); PIN(wiB0[j]); PIN(whA0[j]); PIN(whB0[j]);
        PIN(wiA1[j]); PIN(wiB1[j]); PIN(whA1[j]); PIN(whB1[j]);
        PIN(f1wA[j]); PIN(f1wB[j]);
    }
    PIN(bbA0); PIN(bbB0); PIN(bbA1); PIN(bbB1);
    PIN(f1bA); PIN(f1bB); PIN(f2wA); PIN(f2wB); PIN(f2b);

    // ---- state
    v2f h0p[3], h1p[3];                          // h0(t-1), h1(t-2) gathered
    const v2f Z2 = (v2f){0.0f, 0.0f};
#pragma unroll
    for (int q = 0; q < 3; ++q) { h0p[q] = Z2; h1p[q] = Z2; }
    float c0 = 0.0f, c1 = 0.0f;

    const float* xp = x + (size_t)seq * (512 * 6);
    float*       op = out + (size_t)seq * 512;

    // unit-ordered gather: h[unit j] -> slot j on every lane
#define GATHER(HP_, HV_)                                                        \
    {                                                                           \
        float u_ = dppf<DPP_X8>(HV_);                                           \
        float hl = lowq ? (HV_) : u_;                                           \
        float hh = lowq ? u_ : (HV_);                                           \
        HP_[0] = (v2f){ dppf<DPP_B0>(hl), dppf<DPP_B1>(hl) };                   \
        HP_[1] = (v2f){ dppf<DPP_B2>(hl), dppf<DPP_B3>(hl) };                   \
        HP_[2] = (v2f){ dppf<DPP_B0>(hh), dppf<DPP_B1>(hh) };                   \
    }

    float exi, exf, exg, exo;     // hoisted exp2 of gates0 preacts (next cell0)

    // close gates0 accumulators and hoist their exps
#define CLOSE0()                                                                \
    {                                                                           \
        v2f gA0n, gB0n;                                                         \
        PKADD(gA0n, xgA, xgA2);                                                 \
        PKADD(gB0n, xgB, xgB2);                                                 \
        exi = __builtin_amdgcn_exp2f(gA0n.x);                                   \
        exf = __builtin_amdgcn_exp2f(gA0n.y);                                   \
        exg = __builtin_amdgcn_exp2f(gB0n.x);                                   \
        exo = __builtin_amdgcn_exp2f(gB0n.y);                                   \
    }

    v2f xgA, xgA2, xgB, xgB2;     // gates0 accumulators for the next cell0

    // ---- prologue: cell0(0) + gates0(1) hoist. (cell1 lags one step.)
    {
        v2f x0[3], x1[3];
        x0[0] = *(const v2f*)(xp + 0); x0[1] = *(const v2f*)(xp + 2); x0[2] = *(const v2f*)(xp + 4);
        x1[0] = *(const v2f*)(xp + 6); x1[1] = *(const v2f*)(xp + 8); x1[2] = *(const v2f*)(xp + 10);
        // gates0(0) = bias + x(0)-part (wh-part zero: h0(-1)=0)
        xgA = bbA0; xgA2 = Z2; xgB = bbB0; xgB2 = Z2;
        ACC12(xgA, xgA2, wiA0, x0);
        ACC12(xgB, xgB2, wiB0, x0);
        CLOSE0();
        // cell0(0)
        float i0 = sig_from_e(exi), f0 = sig_from_e(exf);
        float g0 = tanh_from_e(exg), o0 = sig_from_e(exo);
        c0 = fmaf(f0, c0, i0 * g0);
        float h0_ = o0 * tanh_pre(TL2E * c0);
        GATHER(h0p, h0_);
        // gates0(1) = bias + x(1)-part + wh0*h0(0); close; hoist
        xgA = bbA0; xgA2 = Z2; xgB = bbB0; xgB2 = Z2;
        ACC12(xgA, xgA2, wiA0, x1);
        ACC12(xgB, xgB2, wiB0, x1);
        ACC12(xgA, xgA2, whA0, h0p);
        ACC12(xgB, xgB2, whB0, h0p);
        CLOSE0();
    }

    // ---- x prefetch: xq[j] holds x(T+j+2) entering main-loop iteration T
    v2f xq[4][3];
#pragma unroll
    for (int j = 0; j < 4; ++j) {
        const float* q = xp + (j + 2) * 6;
        xq[j][0] = *(const v2f*)(q + 0);
        xq[j][1] = *(const v2f*)(q + 2);
        xq[j][2] = *(const v2f*)(q + 4);
    }

    // Body for step t: A cell1(t-1) | B cell0(t) | C gates0(t+1) | D FC(t-1).
    // XC1_ = x(t+1) slot (v2f[3]); DOPF_/PF_: prefetch; DOB_/DOC_ flags.
#define BODY(XC1_, PF_, DOPF_, DOB_, DOC_, YDST_)                               \
    {                                                                           \
        v2f nx0 = Z2, nx1 = Z2, nx2 = Z2;                                       \
        if (DOPF_) {                                                            \
            const float* xr_ = xp + (PF_) * 6;                                  \
            nx0 = *(const v2f*)(xr_ + 0);                                       \
            nx1 = *(const v2f*)(xr_ + 2);                                       \
            nx2 = *(const v2f*)(xr_ + 4);                                       \
        }                                                                       \
        /* A: cell1(t-1) gate FMAs -- all inputs ready at body start */         \
        v2f pA = bbA1, pA2 = Z2, pB = bbB1, pB2 = Z2;                           \
        ACC12(pA, pA2, whA1, h1p);                                              \
        ACC12(pB, pB2, whB1, h1p);                                              \
        ACC12(pA, pA2, wiA1, h0p);           /* reads OLD h0p = h0(t-1) */      \
        ACC12(pB, pB2, wiB1, h0p);                                              \
        v2f gA1, gB1;                                                           \
        PKADD(gA1, pA, pA2);                                                    \
        PKADD(gB1, pB, pB2);                                                    \
        float e1i = __builtin_amdgcn_exp2f(gA1.x);                              \
        float e1f = __builtin_amdgcn_exp2f(gA1.y);                              \
        float e1g = __builtin_amdgcn_exp2f(gB1.x);                              \
        float e1o = __builtin_amdgcn_exp2f(gB1.y);                              \
        /* B: cell0(t) from hoisted exps */                                     \
        if (DOB_) {                                                             \
            float i0 = sig_from_e(exi), f0 = sig_from_e(exf);                   \
            float g0 = tanh_from_e(exg), o0 = sig_from_e(exo);                  \
            c0 = fmaf(f0, c0, i0 * g0);                                         \
            float h0_ = o0 * tanh_pre(TL2E * c0);                               \
            GATHER(h0p, h0_);                                                   \
        }                                                                       \
        /* A finish: acts, c1, h1, gather */                                    \
        float i1 = sig_from_e(e1i), f1 = sig_from_e(e1f);                       \
        float g1 = tanh_from_e(e1g), o1 = sig_from_e(e1o);                      \
        c1 = fmaf(f1, c1, i1 * g1);                                             \
        float h1_ = o1 * tanh_pre(TL2E * c1);                                   \
        GATHER(h1p, h1_);                                                       \
        /* C: gates0(t+1) = bias + x(t+1) + wh0*h0(t); close; hoist */          \
        if (DOC_) {                                                             \
            xgA = bbA0; xgA2 = Z2; xgB = bbB0; xgB2 = Z2;                       \
            ACC12(xgA, xgA2, wiA0, XC1_);                                       \
            ACC12(xgB, xgB2, wiB0, XC1_);                                       \
            ACC12(xgA, xgA2, whA0, h0p);                                        \
            ACC12(xgB, xgB2, whB0, h0p);                                        \
            CLOSE0();                                                           \
        }                                                                       \
        /* D: FC on h1p = h1(t-1) */                                            \
        {                                                                       \
            v2f rA = f1bA, rA2 = Z2, rB = f1bB, rB2 = Z2;                       \
            ACC12(rA, rA2, f1wA, h1p);                                          \
            ACC12(rB, rB2, f1wB, h1p);                                          \
            v2f RA, RB;                                                         \
            PKADD(RA, rA, rA2);                                                 \
            PKADD(RB, rB, rB2);                                                 \
            float acc =          fmaxf(RA.x, 0.0f) * f2wA.x;                    \
            acc = fmaf(fmaxf(RA.y, 0.0f), f2wA.y, acc);                         \
            acc = fmaf(fmaxf(RB.x, 0.0f), f2wB.x, acc);                         \
            acc = fmaf(fmaxf(RB.y, 0.0f), f2wB.y, acc);                         \
            acc += dppf<DPP_X1>(acc);                                           \
            acc += dppf<DPP_X2>(acc);                                           \
            acc += dppf<DPP_X8>(acc);                                           \
            YDST_ = fmaxf(acc + f2b, 0.0f);                                     \
        }                                                                       \
        if (DOPF_) { XC1_[0] = nx0; XC1_[1] = nx1; XC1_[2] = nx2; }             \
    }

    float y[4];

    // ---- main loop: t = T+j+1 in 1..508
    for (int T = 0; T < 508; T += 4) {
#pragma unroll
        for (int j = 0; j < 4; ++j) {
            int pf = T + j + 6;                   // prefetch x(t+5)
            if (pf > 511) pf = 511;
            BODY(xq[j], pf, true, true, true, y[j]);   // y(t-1) = y(T+j)
        }
        if (live && ((L & 11) == 0)) {
            float4 yv = make_float4(y[0], y[1], y[2], y[3]);
            *(float4*)(op + T) = yv;              // y(T..T+3)
        }
    }

    // ---- peeled steps t = 509, 510, 511 (+ epilogue cell1(511), FC(511))
    {
        float yp0, yp1, yp2, yp3;
        BODY(xq[0], 511, false, true, true,  yp0);   // t=509: y(508); C(510) uses xq[0]=x(510)
        BODY(xq[1], 511, false, true, true,  yp1);   // t=510: y(509); C(511) uses xq[1]=x(511)
        BODY(xq[2], 511, false, true, false, yp2);   // t=511: y(510); no C
        BODY(xq[3], 511, false, false, false, yp3);  // epilogue: cell1(511) + FC -> y(511)
        if (live && ((L & 11) == 0)) {
            float4 yv = make_float4(yp0, yp1, yp2, yp3);
            *(float4*)(op + 508) = yv;
        }
    }
#undef BODY
#undef GATHER
#undef CLOSE0
}

extern "C" void kernel_launch(void* const* d_in, const int* in_sizes, int n_in,
                              void* d_out, int out_size, void* d_ws, size_t ws_size,
                              hipStream_t stream) {
    const float* x     = (const float*)d_in[0];
    const float* wih0  = (const float*)d_in[1];
    const float* whh0  = (const float*)d_in[2];
    const float* bih0  = (const float*)d_in[3];
    const float* bhh0  = (const float*)d_in[4];
    const float* wih1  = (const float*)d_in[5];
    const float* whh1  = (const float*)d_in[6];
    const float* bih1  = (const float*)d_in[7];
    const float* bhh1  = (const float*)d_in[8];
    const float* fc1w  = (const float*)d_in[9];
    const float* fc1b  = (const float*)d_in[10];
    const float* fc2w  = (const float*)d_in[11];
    const float* fc2b  = (const float*)d_in[12];
    float* out = (float*)d_out;

    const int nbatch = in_sizes[0] / (512 * 6);     // 8192
    const int grid   = (nbatch + 7) / 8;            // 8 seqs per 64-thread wave

    hipLaunchKernelGGL(lstm_dpp8v14, dim3(grid), dim3(64), 0, stream,
                       x, wih0, whh0, bih0, bhh0, wih1, whh1, bih1, bhh1,
                       fc1w, fc1b, fc2w, fc2b, out, nbatch);
}

// Round 15
// 179.483 us; speedup vs baseline: 1.0392x; 1.0392x over previous
//
#include <hip/hip_runtime.h>

// RIIDModelLSTM: 2-layer LSTM (H=6), T=512, B=8192, fused FC(6->32->1) head.
//
// v15 == v13 (BEST, 179.4us) — pure revert of v14's pipeline regression.
// Final ledger: 841 cyc/step = 661 busy (instruction-census floor at the
// 8-lane/1-wave-per-SIMD mapping, which R11/R12 proved uniquely optimal)
// + ~180 serial-chain latency residue. Attack history: x-hoist +19us,
// exp-hoist +2us, chain-rotation 0, FC-defer -3us, layer-pipeline -7us.
// Structure: 8-lane coset/seq, lane p owns unit p (6,7 pad); zero-DS,
// DPP-only cross-lane; v_pk_fma_f32 inline-asm gate math with op_sel
// broadcasts; activation scales folded into weights; gates0(t+1) fully
// accumulated across step t's act0/act1 windows and its exps hoisted to
// step t's tail. 1024 waves = 1 wave/SIMD.

typedef float v2f __attribute__((ext_vector_type(2)));

static constexpr float L2E  = 1.44269504088896340736f;
static constexpr float TL2E = 2.0f * L2E;

#define DPP_QP(a,b,c,d) ((a)|((b)<<2)|((c)<<4)|((d)<<6))
#define DPP_X1  DPP_QP(1,0,3,2)   // quad_perm xor-1
#define DPP_X2  DPP_QP(2,3,0,1)   // quad_perm xor-2
#define DPP_B0  DPP_QP(0,0,0,0)   // quad bcast lane0
#define DPP_B1  DPP_QP(1,1,1,1)
#define DPP_B2  DPP_QP(2,2,2,2)
#define DPP_B3  DPP_QP(3,3,3,3)
#define DPP_X8  0x128             // row_ror:8 = lane xor 8 inside 16-row

template<int CTRL>
__device__ __forceinline__ float dppf(float v) {
    return __int_as_float(__builtin_amdgcn_update_dpp(
        0, __float_as_int(v), CTRL, 0xF, 0xF, true));
}

#define PIN(v) asm volatile("" : "+v"(v))

// d += a * (b.lo, b.lo)   [VOP3P op_sel: src1 lo for both halves]
#define PKFMA_LO(d,a,b) asm("v_pk_fma_f32 %0, %1, %2, %0 op_sel:[0,0,0] op_sel_hi:[1,0,1]" : "+v"(d) : "v"(a), "v"(b))
// d += a * (b.hi, b.hi)
#define PKFMA_HI(d,a,b) asm("v_pk_fma_f32 %0, %1, %2, %0 op_sel:[0,1,0] op_sel_hi:[1,1,1]" : "+v"(d) : "v"(a), "v"(b))
#define PKADD(d,a,b)    asm("v_pk_add_f32 %0, %1, %2" : "=v"(d) : "v"(a), "v"(b))

// sigmoid from a pre-computed e = exp2(-L2E*x):  1/(1+e)
__device__ __forceinline__ float sig_from_e(float e) {
    return __builtin_amdgcn_rcpf(1.0f + e);
}
// tanh from e = exp2(2*L2E*x):  1 - 2/(1+e)
__device__ __forceinline__ float tanh_from_e(float e) {
    return fmaf(-2.0f, __builtin_amdgcn_rcpf(1.0f + e), 1.0f);
}
// full forms (used for cell-1 gates and tanh(c), which can't be hoisted)
__device__ __forceinline__ float sig_pre(float a) {
    return __builtin_amdgcn_rcpf(1.0f + __builtin_amdgcn_exp2f(a));
}
__device__ __forceinline__ float tanh_pre(float a) {
    return fmaf(-2.0f, __builtin_amdgcn_rcpf(1.0f + __builtin_amdgcn_exp2f(a)), 1.0f);
}

extern "C" __global__ void __launch_bounds__(64)
__attribute__((amdgpu_waves_per_eu(1, 1)))
lstm_dpp8v15(const float* __restrict__ x,
             const float* __restrict__ wih0, const float* __restrict__ whh0,
             const float* __restrict__ bih0, const float* __restrict__ bhh0,
             const float* __restrict__ wih1, const float* __restrict__ whh1,
             const float* __restrict__ bih1, const float* __restrict__ bhh1,
             const float* __restrict__ fc1w, const float* __restrict__ fc1b,
             const float* __restrict__ fc2w, const float* __restrict__ fc2b,
             float* __restrict__ out, int nbatch)
{
    const int L   = threadIdx.x;                 // 0..63
    const int l   = L & 15;
    const int row = L >> 4;                      // 0..3
    const int cst = (l >> 2) & 1;                // coset within row
    const int p   = (l & 3) | ((l >> 3) << 2);   // position in coset, 0..7
    const bool lowq = ((L >> 3) & 1) == 0;       // lane in units-0..3 quad

    int seq = blockIdx.x * 8 + row * 2 + cst;
    const bool live = (seq < nbatch);
    if (!live) seq = nbatch - 1;

    const float km = (p < 6) ? 1.0f : 0.0f;      // pad lanes 6,7
    const int   k  = (p < 6) ? p : 0;
    const int ir = k, fr = 6 + k, gr = 12 + k, orr = 18 + k;  // i,f,g,o rows

    // ---- weights. Gate pairs A=[i,f] (sigmoid,-L2E | sigmoid,-L2E),
    //               B=[g,o] (tanh,+2L2E | sigmoid,-L2E). Unit-ordered slots.
    v2f wiA0[6], wiB0[6];
    v2f whA0[6], whB0[6], wiA1[6], wiB1[6], whA1[6], whB1[6], f1wA[6], f1wB[6];
#pragma unroll
    for (int j = 0; j < 6; ++j) {
        wiA0[j] = (v2f){ wih0[ir*6+j]*(-L2E)*km,  wih0[fr*6+j]*(-L2E)*km };
        wiB0[j] = (v2f){ wih0[gr*6+j]*( TL2E)*km, wih0[orr*6+j]*(-L2E)*km };
        whA0[j] = (v2f){ whh0[ir*6+j]*(-L2E)*km,  whh0[fr*6+j]*(-L2E)*km };
        whB0[j] = (v2f){ whh0[gr*6+j]*( TL2E)*km, whh0[orr*6+j]*(-L2E)*km };
        wiA1[j] = (v2f){ wih1[ir*6+j]*(-L2E)*km,  wih1[fr*6+j]*(-L2E)*km };
        wiB1[j] = (v2f){ wih1[gr*6+j]*( TL2E)*km, wih1[orr*6+j]*(-L2E)*km };
        whA1[j] = (v2f){ whh1[ir*6+j]*(-L2E)*km,  whh1[fr*6+j]*(-L2E)*km };
        whB1[j] = (v2f){ whh1[gr*6+j]*( TL2E)*km, whh1[orr*6+j]*(-L2E)*km };
        f1wA[j] = (v2f){ fc1w[(4*p+0)*6+j], fc1w[(4*p+1)*6+j] };
        f1wB[j] = (v2f){ fc1w[(4*p+2)*6+j], fc1w[(4*p+3)*6+j] };
    }
    v2f bbA0 = (v2f){ (bih0[ir]+bhh0[ir])*(-L2E)*km,  (bih0[fr]+bhh0[fr])*(-L2E)*km };
    v2f bbB0 = (v2f){ (bih0[gr]+bhh0[gr])*( TL2E)*km, (bih0[orr]+bhh0[orr])*(-L2E)*km };
    v2f bbA1 = (v2f){ (bih1[ir]+bhh1[ir])*(-L2E)*km,  (bih1[fr]+bhh1[fr])*(-L2E)*km };
    v2f bbB1 = (v2f){ (bih1[gr]+bhh1[gr])*( TL2E)*km, (bih1[orr]+bhh1[orr])*(-L2E)*km };
    v2f f1bA = (v2f){ fc1b[4*p+0], fc1b[4*p+1] };
    v2f f1bB = (v2f){ fc1b[4*p+2], fc1b[4*p+3] };
    v2f f2wA = (v2f){ fc2w[4*p+0], fc2w[4*p+1] };
    v2f f2wB = (v2f){ fc2w[4*p+2], fc2w[4*p+3] };
    float f2b = fc2b[0];

#pragma unroll
    for (int j = 0; j < 6; ++j) {
        PIN(wiA0[j]); PIN(wiB0[j]); PIN(whA0[j]); PIN(whB0[j]);
        PIN(wiA1[j]); PIN(wiB1[j]); PIN(whA1[j]); PIN(whB1[j]);
        PIN(f1wA[j]); PIN(f1wB[j]);
    }
    PIN(bbA0); PIN(bbB0); PIN(bbA1); PIN(bbB1);
    PIN(f1bA); PIN(f1bB); PIN(f2wA); PIN(f2wB); PIN(f2b);

    // ---- state: h packed pairwise, units (0,1),(2,3),(4,5)
    v2f h0p[3], h1p[3];
    const v2f Z2 = (v2f){0.0f, 0.0f};
#pragma unroll
    for (int q = 0; q < 3; ++q) { h0p[q] = Z2; h1p[q] = Z2; }
    float c0 = 0.0f, c1 = 0.0f;

    const float* xp = x + (size_t)seq * (512 * 6);
    float*       op = out + (size_t)seq * 512;

    // ---- 4-deep x prefetch, pairs (x0,x1),(x2,x3),(x4,x5) as v2f
    v2f xq[4][3];
#pragma unroll
    for (int j = 0; j < 4; ++j) {
        const float* q = xp + j * 6;
        xq[j][0] = *(const v2f*)(q + 0);
        xq[j][1] = *(const v2f*)(q + 2);
        xq[j][2] = *(const v2f*)(q + 4);
    }

    // unit-ordered gather: h[unit j] -> slot j on every lane, 6 slots
#define GATHER(HP_, HV_)                                                        \
    {                                                                           \
        float u_ = dppf<DPP_X8>(HV_);            /* partner quad's h */         \
        float hl = lowq ? (HV_) : u_;            /* units 0-3 @ quad pos */     \
        float hh = lowq ? u_ : (HV_);            /* units 4-7 @ quad pos */     \
        HP_[0] = (v2f){ dppf<DPP_B0>(hl), dppf<DPP_B1>(hl) };                   \
        HP_[1] = (v2f){ dppf<DPP_B2>(hl), dppf<DPP_B3>(hl) };                   \
        HP_[2] = (v2f){ dppf<DPP_B0>(hh), dppf<DPP_B1>(hh) };                   \
    }

    // ---- cell0 gate-preactivation accumulators + HOISTED exps for step 0.
    v2f xgA, xgA2, xgB, xgB2;
    float exi, exf, exg, exo;     // exp2 of gate0 preacts for the NEXT step
    {
        xgA = bbA0; xgA2 = Z2; xgB = bbB0; xgB2 = Z2;
        PKFMA_LO(xgA, wiA0[0], xq[0][0]); PKFMA_HI(xgA2, wiA0[1], xq[0][0]);
        PKFMA_LO(xgA, wiA0[2], xq[0][1]); PKFMA_HI(xgA2, wiA0[3], xq[0][1]);
        PKFMA_LO(xgA, wiA0[4], xq[0][2]); PKFMA_HI(xgA2, wiA0[5], xq[0][2]);
        PKFMA_LO(xgB, wiB0[0], xq[0][0]); PKFMA_HI(xgB2, wiB0[1], xq[0][0]);
        PKFMA_LO(xgB, wiB0[2], xq[0][1]); PKFMA_HI(xgB2, wiB0[3], xq[0][1]);
        PKFMA_LO(xgB, wiB0[4], xq[0][2]); PKFMA_HI(xgB2, wiB0[5], xq[0][2]);
        v2f gA0, gB0;
        PKADD(gA0, xgA, xgA2);
        PKADD(gB0, xgB, xgB2);
        exi = __builtin_amdgcn_exp2f(gA0.x);
        exf = __builtin_amdgcn_exp2f(gA0.y);
        exg = __builtin_amdgcn_exp2f(gB0.x);
        exo = __builtin_amdgcn_exp2f(gB0.y);
    }

    float y[4];

    for (int T = 0; T < 512; T += 4) {
        const int Tn = (T < 508) ? T + 4 : 508;   // clamped prefetch base
#pragma unroll
        for (int j = 0; j < 4; ++j) {
            // -- issue x[T+j+4] loads early (consumed next outer iter)
            const float* xr = xp + (Tn + j) * 6;
            v2f nx0 = *(const v2f*)(xr + 0);
            v2f nx1 = *(const v2f*)(xr + 2);
            v2f nx2 = *(const v2f*)(xr + 4);

            // -- act0 opens DIRECTLY with rcps (exps hoisted to prev step)
            float i0 = sig_from_e(exi), f0 = sig_from_e(exf);
            float g0 = tanh_from_e(exg), o0 = sig_from_e(exo);

            // -- act0-window filler 1: cell1 recurrent partial (h1p(t-1))
            v2f pA = bbA1, pA2 = Z2, pB = bbB1, pB2 = Z2;
            PKFMA_LO(pA, whA1[0], h1p[0]); PKFMA_HI(pA2, whA1[1], h1p[0]);
            PKFMA_LO(pA, whA1[2], h1p[1]); PKFMA_HI(pA2, whA1[3], h1p[1]);
            PKFMA_LO(pA, whA1[4], h1p[2]); PKFMA_HI(pA2, whA1[5], h1p[2]);
            PKFMA_LO(pB, whB1[0], h1p[0]); PKFMA_HI(pB2, whB1[1], h1p[0]);
            PKFMA_LO(pB, whB1[2], h1p[1]); PKFMA_HI(pB2, whB1[3], h1p[1]);
            PKFMA_LO(pB, whB1[4], h1p[2]); PKFMA_HI(pB2, whB1[5], h1p[2]);

            // -- act0-window filler 2: x-part of gates0(t+1) into fresh regs
            {
                const v2f* xn = xq[(j + 1) & 3];
                v2f tA = bbA0, tA2 = Z2, tB = bbB0, tB2 = Z2;
                PKFMA_LO(tA, wiA0[0], xn[0]); PKFMA_HI(tA2, wiA0[1], xn[0]);
                PKFMA_LO(tA, wiA0[2], xn[1]); PKFMA_HI(tA2, wiA0[3], xn[1]);
                PKFMA_LO(tA, wiA0[4], xn[2]); PKFMA_HI(tA2, wiA0[5], xn[2]);
                PKFMA_LO(tB, wiB0[0], xn[0]); PKFMA_HI(tB2, wiB0[1], xn[0]);
                PKFMA_LO(tB, wiB0[2], xn[1]); PKFMA_HI(tB2, wiB0[3], xn[1]);
                PKFMA_LO(tB, wiB0[4], xn[2]); PKFMA_HI(tB2, wiB0[5], xn[2]);
                xgA = tA; xgA2 = tA2; xgB = tB; xgB2 = tB2;
            }

            c0 = fmaf(f0, c0, i0 * g0);
            float h0 = o0 * tanh_pre(TL2E * c0);

            GATHER(h0p, h0);

            // -- cell 1 finish (input part over fresh h0)
            PKFMA_LO(pA, wiA1[0], h0p[0]); PKFMA_HI(pA2, wiA1[1], h0p[0]);
            PKFMA_LO(pA, wiA1[2], h0p[1]); PKFMA_HI(pA2, wiA1[3], h0p[1]);
            PKFMA_LO(pA, wiA1[4], h0p[2]); PKFMA_HI(pA2, wiA1[5], h0p[2]);
            PKFMA_LO(pB, wiB1[0], h0p[0]); PKFMA_HI(pB2, wiB1[1], h0p[0]);
            PKFMA_LO(pB, wiB1[2], h0p[1]); PKFMA_HI(pB2, wiB1[3], h0p[1]);
            PKFMA_LO(pB, wiB1[4], h0p[2]); PKFMA_HI(pB2, wiB1[5], h0p[2]);
            v2f gA1, gB1;
            PKADD(gA1, pA, pA2);
            PKADD(gB1, pB, pB2);

            float i1 = sig_pre(gA1.x), f1 = sig_pre(gA1.y);
            float g1 = tanh_pre(gB1.x), o1 = sig_pre(gB1.y);

            // -- act1-window filler: wh-part of gates0(t+1) (h0p = h0(t))
            PKFMA_LO(xgA, whA0[0], h0p[0]);  PKFMA_HI(xgA2, whA0[1], h0p[0]);
            PKFMA_LO(xgA, whA0[2], h0p[1]);  PKFMA_HI(xgA2, whA0[3], h0p[1]);
            PKFMA_LO(xgA, whA0[4], h0p[2]);  PKFMA_HI(xgA2, whA0[5], h0p[2]);
            PKFMA_LO(xgB, whB0[0], h0p[0]);  PKFMA_HI(xgB2, whB0[1], h0p[0]);
            PKFMA_LO(xgB, whB0[2], h0p[1]);  PKFMA_HI(xgB2, whB0[3], h0p[1]);
            PKFMA_LO(xgB, whB0[4], h0p[2]);  PKFMA_HI(xgB2, whB0[5], h0p[2]);

            c1 = fmaf(f1, c1, i1 * g1);
            float h1 = o1 * tanh_pre(TL2E * c1);

            GATHER(h1p, h1);

            // -- close gates0(t+1) and issue its 4 exps now (off next step's
            //    critical chain). Bit-identical values.
            {
                v2f gA0n, gB0n;
                PKADD(gA0n, xgA, xgA2);
                PKADD(gB0n, xgB, xgB2);
                exi = __builtin_amdgcn_exp2f(gA0n.x);
                exf = __builtin_amdgcn_exp2f(gA0n.y);
                exg = __builtin_amdgcn_exp2f(gB0n.x);
                exo = __builtin_amdgcn_exp2f(gB0n.y);
            }

            // -- FC head on fresh h1 (fills the exp-hoist latency window)
            v2f rA = f1bA, rA2 = Z2, rB = f1bB, rB2 = Z2;
            PKFMA_LO(rA, f1wA[0], h1p[0]); PKFMA_HI(rA2, f1wA[1], h1p[0]);
            PKFMA_LO(rA, f1wA[2], h1p[1]); PKFMA_HI(rA2, f1wA[3], h1p[1]);
            PKFMA_LO(rA, f1wA[4], h1p[2]); PKFMA_HI(rA2, f1wA[5], h1p[2]);
            PKFMA_LO(rB, f1wB[0], h1p[0]); PKFMA_HI(rB2, f1wB[1], h1p[0]);
            PKFMA_LO(rB, f1wB[2], h1p[1]); PKFMA_HI(rB2, f1wB[3], h1p[1]);
            PKFMA_LO(rB, f1wB[4], h1p[2]); PKFMA_HI(rB2, f1wB[5], h1p[2]);
            v2f RA, RB;
            PKADD(RA, rA, rA2);
            PKADD(RB, rB, rB2);
            float acc =          fmaxf(RA.x, 0.0f) * f2wA.x;
            acc = fmaf(fmaxf(RA.y, 0.0f), f2wA.y, acc);
            acc = fmaf(fmaxf(RB.x, 0.0f), f2wB.x, acc);
            acc = fmaf(fmaxf(RB.y, 0.0f), f2wB.y, acc);
            // butterfly reduce over the 8-lane coset (pure VALU)
            acc += dppf<DPP_X1>(acc);
            acc += dppf<DPP_X2>(acc);
            acc += dppf<DPP_X8>(acc);
            y[j] = fmaxf(acc + f2b, 0.0f);

            // -- rotate x prefetch
            xq[j][0] = nx0; xq[j][1] = nx1; xq[j][2] = nx2;
        }
        // -- one coalesced 16B out-store per 4 steps (lane p==0 of each coset)
        if (live && ((L & 11) == 0)) {
            float4 yv = make_float4(y[0], y[1], y[2], y[3]);
            *(float4*)(op + T) = yv;
        }
    }
}

extern "C" void kernel_launch(void* const* d_in, const int* in_sizes, int n_in,
                              void* d_out, int out_size, void* d_ws, size_t ws_size,
                              hipStream_t stream) {
    const float* x     = (const float*)d_in[0];
    const float* wih0  = (const float*)d_in[1];
    const float* whh0  = (const float*)d_in[2];
    const float* bih0  = (const float*)d_in[3];
    const float* bhh0  = (const float*)d_in[4];
    const float* wih1  = (const float*)d_in[5];
    const float* whh1  = (const float*)d_in[6];
    const float* bih1  = (const float*)d_in[7];
    const float* bhh1  = (const float*)d_in[8];
    const float* fc1w  = (const float*)d_in[9];
    const float* fc1b  = (const float*)d_in[10];
    const float* fc2w  = (const float*)d_in[11];
    const float* fc2b  = (const float*)d_in[12];
    float* out = (float*)d_out;

    const int nbatch = in_sizes[0] / (512 * 6);     // 8192
    const int grid   = (nbatch + 7) / 8;            // 8 seqs per 64-thread wave

    hipLaunchKernelGGL(lstm_dpp8v15, dim3(grid), dim3(64), 0, stream,
                       x, wih0, whh0, bih0, bhh0, wih1, whh1, bih1, bhh1,
                       fc1w, fc1b, fc2w, fc2b, out, nbatch);
}